// Round 7
// baseline (1145.365 us; speedup 1.0000x reference)
//
#include <hip/hip_runtime.h>
#include <hip/hip_bf16.h>

#define NB   524288   // nodes (B)
#define NC   256      // clusters (C)
#define ND   128      // feature dim (D)

typedef __attribute__((ext_vector_type(4))) float f32x4;
typedef __attribute__((ext_vector_type(8))) short bf16x8;

// ---------- fast math helpers ----------
__device__ inline float fast_exp(float x)  { return exp2f(x * 1.4426950408889634f); }
__device__ inline float fast_sigmoid(float x) { return __builtin_amdgcn_rcpf(1.f + fast_exp(-x)); }
__device__ inline float fast_tanh(float x) { return 1.f - 2.f * __builtin_amdgcn_rcpf(1.f + fast_exp(2.f * x)); }

__device__ inline unsigned short f2bf(float f) {
    unsigned u = __float_as_uint(f);
    u += 0x7FFFu + ((u >> 16) & 1u);   // round-to-nearest-even
    return (unsigned short)(u >> 16);
}

__device__ inline bf16x8 pack8(const float* __restrict__ p) {
    float4 a = *(const float4*)p;
    float4 b = *(const float4*)(p + 4);
    bf16x8 r;
    r[0] = (short)f2bf(a.x); r[1] = (short)f2bf(a.y);
    r[2] = (short)f2bf(a.z); r[3] = (short)f2bf(a.w);
    r[4] = (short)f2bf(b.x); r[5] = (short)f2bf(b.y);
    r[6] = (short)f2bf(b.z); r[7] = (short)f2bf(b.w);
    return r;
}

// ---------------- K1: per-cluster precompute ----------------
__global__ __launch_bounds__(128) void k1_cluster_prep(
    const float* __restrict__ g, const float* __restrict__ Wq,
    const float* __restrict__ attn_bias,
    const float* __restrict__ Fs_w, const float* __restrict__ Fs_b,
    const float* __restrict__ G1_w, const float* __restrict__ G1_b,
    float* __restrict__ g_trans, float* __restrict__ gG1, float* __restrict__ qb) {
    const int c = blockIdx.x, d = threadIdx.x;
    __shared__ float g_lds[ND];
    __shared__ float gt_lds[ND];
    g_lds[d] = g[c * ND + d];
    __syncthreads();
    float accF = Fs_b[d], accQ = attn_bias[d];
    const float* fr = Fs_w + d * ND;
    const float* qr = Wq + d * ND;
    for (int k = 0; k < ND; ++k) {
        float gv = g_lds[k];
        accF += fr[k] * gv;
        accQ += qr[k] * gv;
    }
    float gt = fast_tanh(accF);
    g_trans[c * ND + d] = gt;
    gt_lds[d] = gt;
    qb[c * ND + d] = accQ;
    __syncthreads();
    float accG = G1_b[d];
    const float* gr = G1_w + d * ND;
    for (int k = 0; k < ND; ++k) accG += gr[k] * gt_lds[k];
    gG1[c * ND + d] = accG;
}

// ---------------- K2: pass 1 — 8-wave role-split, barrier-free ----------------
// Block = 512 threads = 8 waves, owns 256 nodes (16 tiles of 16).
// Waves 0-3 (role 0): k = h@Wk.T for dims [32w,32w+32) + score partial (atomic).
// Waves 4-7 (role 1): hH1 = h@H1_w.T for dims [32w',32w'+32) + gate + outh write.
// Weight frags: 8 x bf16x8 = 32 VGPR per wave -> high occupancy.
// Ws_b dropped (constant shift cancels in segment softmax). No segment max
// needed downstream: |score| <= sum|Ws_w| (~9) so exp(score) is f32-safe.
__global__ __launch_bounds__(512, 6) void k2_pass1(
    const float* __restrict__ h, const int* __restrict__ cid,
    const float* __restrict__ Wk, const float* __restrict__ H1w,
    const float* __restrict__ H1b, const float* __restrict__ Wsw,
    const float* __restrict__ g_trans, const float* __restrict__ gG1,
    const float* __restrict__ qb,
    float* __restrict__ outh, float* __restrict__ score) {
    const int tid = threadIdx.x;
    const int w = tid >> 6, l = tid & 63;
    const int l15 = l & 15, lg = l >> 4;
    const int role = w >> 2;           // 0: k/score, 1: hH1/gate
    const int w4 = w & 3;              // dim group: dims [32*w4, 32*w4+32)

    const float* Wmat = role ? H1w : Wk;
    // B-frags for the two 16-dim tiles this wave owns (4 K-chunks each)
    bf16x8 bw[2][4];
#pragma unroll
    for (int t2 = 0; t2 < 2; ++t2) {
        const int trow = (2 * w4 + t2) * 16 + l15;
#pragma unroll
        for (int c = 0; c < 4; ++c)
            bw[t2][c] = pack8(Wmat + trow * ND + c * 32 + lg * 8);
    }
    const int d0 = 32 * w4 + l15, d1 = d0 + 16;
    // role-specific constants
    const float c0 = role ? H1b[d0] : Wsw[d0];
    const float c1 = role ? H1b[d1] : Wsw[d1];

    const int nb0 = blockIdx.x * 256;

    for (int it = 0; it < 16; ++it) {
        const int nb = nb0 + it * 16;
        // A-frags: lane row (l&15), cols c*32+(l>>4)*8
        bf16x8 af[4];
        const float* hrow = h + (size_t)(nb + l15) * ND + lg * 8;
#pragma unroll
        for (int c = 0; c < 4; ++c) af[c] = pack8(hrow + c * 32);
        // cluster ids for this lane-group's 4 nodes (broadcast int4)
        int4 cc4 = *(const int4*)(cid + nb + lg * 4);

        f32x4 acc0 = {0.f, 0.f, 0.f, 0.f}, acc1 = {0.f, 0.f, 0.f, 0.f};
#pragma unroll
        for (int c = 0; c < 4; ++c) {
            acc0 = __builtin_amdgcn_mfma_f32_16x16x32_bf16(af[c], bw[0][c], acc0, 0, 0, 0);
            acc1 = __builtin_amdgcn_mfma_f32_16x16x32_bf16(af[c], bw[1][c], acc1, 0, 0, 0);
        }
        // C/D layout: col = lane&15 (dim in tile), row = (lane>>4)*4 + reg (node)
        const int ccs[4] = {cc4.x, cc4.y, cc4.z, cc4.w};
        if (role == 0) {
#pragma unroll
            for (int r = 0; r < 4; ++r) {
                const int node = nb + lg * 4 + r;
                const float* qrow = qb + ccs[r] * ND;
                float sp = fast_tanh(acc0[r] + qrow[d0]) * c0
                         + fast_tanh(acc1[r] + qrow[d1]) * c1;
                sp += __shfl_xor(sp, 1);
                sp += __shfl_xor(sp, 2);
                sp += __shfl_xor(sp, 4);
                sp += __shfl_xor(sp, 8);
                if (l15 == 0) unsafeAtomicAdd(&score[node], sp);
            }
        } else {
#pragma unroll
            for (int r = 0; r < 4; ++r) {
                const int node = nb + lg * 4 + r;
                const float* grow = gG1 + ccs[r] * ND;
                const float* trow = g_trans + ccs[r] * ND;
                const float* hrw  = h + (size_t)node * ND;
                float gg0 = grow[d0], gg1 = grow[d1];
                float gt0 = trow[d0], gt1 = trow[d1];
                float hv0 = hrw[d0],  hv1 = hrw[d1];
                float z0 = fast_sigmoid(acc0[r] + c0 + gg0);
                float z1 = fast_sigmoid(acc1[r] + c1 + gg1);
                outh[(size_t)node * ND + d0] = (1.f - z0) * hv0 + z0 * gt0;
                outh[(size_t)node * ND + d1] = (1.f - z1) * hv1 + z1 * gt1;
            }
        }
    }
}

// ---------------- K4: pass 2 — weighted segment sum (no max needed) ----------------
// Each block owns a QUARTER of the dims (32) for 2048 nodes.
// LDS accumulator 256 x 33 (pad kills bank conflicts) ~34 KB -> 4 blocks/CU.
__global__ __launch_bounds__(256) void k4_pass2(
    const float* __restrict__ h, const int* __restrict__ cid,
    const float* __restrict__ score,
    float* __restrict__ ctx_raw, float* __restrict__ denom) {
    __shared__ float cloc[NC * 33];
    __shared__ float dloc[NC];
    const int t = threadIdx.x, w = t >> 6, l = t & 63;
    const int q = blockIdx.x & 3;        // dim quarter
    const int bg = blockIdx.x >> 2;      // node group (2048 nodes)
    for (int i = t; i < NC * 33; i += 256) cloc[i] = 0.f;
    dloc[t] = 0.f;
    __syncthreads();
    const int colbase = q * 32 + (l & 7) * 4;   // 4 consecutive dims per lane
    const int n0 = bg * 2048 + w * 512;
#pragma unroll 4
    for (int nn = 0; nn < 512; nn += 8) {
        const int node = n0 + nn + (l >> 3);    // 8 nodes per wave-instruction
        float e = fast_exp(score[node]);        // bounded: |score| <= ~9
        int c = cid[node];
        float4 hv = *(const float4*)(h + (size_t)node * ND + colbase);
        const int base = c * 33 + (l & 7) * 4;
        atomicAdd(&cloc[base + 0], e * hv.x);
        atomicAdd(&cloc[base + 1], e * hv.y);
        atomicAdd(&cloc[base + 2], e * hv.z);
        atomicAdd(&cloc[base + 3], e * hv.w);
        if ((l & 7) == 0 && q == 0) atomicAdd(&dloc[c], e);
    }
    __syncthreads();
    for (int i = t; i < NC * 32; i += 256) {
        const int c = i >> 5, col = i & 31;
        unsafeAtomicAdd(&ctx_raw[c * ND + q * 32 + col], cloc[c * 33 + col]);
    }
    if (q == 0) unsafeAtomicAdd(&denom[t], dloc[t]);
}

// ---------------- K5: finalize virtual nodes ----------------
__global__ __launch_bounds__(128) void k5_final(
    const float* __restrict__ g, const float* __restrict__ ctx_raw,
    const float* __restrict__ denom,
    const float* __restrict__ W_w, const float* __restrict__ W_b,
    const float* __restrict__ H2_w, const float* __restrict__ H2_b,
    const float* __restrict__ G2_w, const float* __restrict__ G2_b,
    float* __restrict__ out_g) {
    const int c = blockIdx.x, d = threadIdx.x;
    __shared__ float ctx_l[ND], ht_l[ND], g_l[ND];
    float den = fmaxf(denom[c], 1e-20f);
    float ctxv = ctx_raw[c * ND + d] / den;
    ctx_l[d] = ctxv;
    g_l[d] = g[c * ND + d];
    __syncthreads();
    float acc = W_b[d];
    const float* wr = W_w + d * ND;
    for (int k = 0; k < ND; ++k) acc += wr[k] * ctx_l[k];
    float ht = fast_tanh(acc);
    ht_l[d] = ht;
    __syncthreads();
    float acc2 = H2_b[d] + G2_b[d];
    const float* h2r = H2_w + d * ND;
    const float* g2r = G2_w + d * ND;
    for (int k = 0; k < ND; ++k) acc2 += h2r[k] * g_l[k] + g2r[k] * ht_l[k];
    float z = fast_sigmoid(acc2);
    out_g[c * ND + d] = (1.f - z) * g_l[d] + z * ht;
}

extern "C" void kernel_launch(void* const* d_in, const int* in_sizes, int n_in,
                              void* d_out, int out_size, void* d_ws, size_t ws_size,
                              hipStream_t stream) {
    const float* h     = (const float*)d_in[0];
    const float* g     = (const float*)d_in[1];
    const int*   cid   = (const int*)d_in[2];
    const float* Wq    = (const float*)d_in[3];
    const float* Wk    = (const float*)d_in[4];
    const float* attnb = (const float*)d_in[5];
    const float* Ws_w  = (const float*)d_in[6];
    const float* W_w   = (const float*)d_in[8];
    const float* W_b   = (const float*)d_in[9];
    const float* Fs_w  = (const float*)d_in[10];
    const float* Fs_b  = (const float*)d_in[11];
    const float* H1_w  = (const float*)d_in[12];
    const float* H1_b  = (const float*)d_in[13];
    const float* G1_w  = (const float*)d_in[14];
    const float* G1_b  = (const float*)d_in[15];
    const float* H2_w  = (const float*)d_in[16];
    const float* H2_b  = (const float*)d_in[17];
    const float* G2_w  = (const float*)d_in[18];
    const float* G2_b  = (const float*)d_in[19];
    float* out = (float*)d_out;
    float* ws  = (float*)d_ws;

    // ws layout (floats)
    float* g_trans = ws;               // 32768
    float* gG1     = ws + 32768;       // 32768
    float* qb      = ws + 65536;       // 32768
    float* score   = ws + 98304;       // 524288 (atomic-accumulated: must be 0)
    float* denom   = ws + 622592;      // 256
    float* ctx_raw = ws + 622848;      // 32768
    // zero all atomic-accumulated regions (score, denom, ctx_raw contiguous)
    (void)hipMemsetAsync(ws + 98304, 0, (524288 + 256 + 32768) * sizeof(float), stream);

    k1_cluster_prep<<<NC, ND, 0, stream>>>(g, Wq, attnb, Fs_w, Fs_b, G1_w, G1_b,
                                           g_trans, gG1, qb);
    k2_pass1<<<2048, 512, 0, stream>>>(h, cid, Wk, H1_w, H1_b, Ws_w,
                                       g_trans, gG1, qb, out, score);
    k4_pass2<<<1024, 256, 0, stream>>>(h, cid, score, ctx_raw, denom);
    k5_final<<<NC, ND, 0, stream>>>(g, ctx_raw, denom, W_w, W_b,
                                    H2_w, H2_b, G2_w, G2_b,
                                    out + (size_t)NB * ND);
}